// Round 6
// baseline (666.744 us; speedup 1.0000x reference)
//
#include <hip/hip_runtime.h>
#include <math.h>

#define NB 8
#define NN 10000
#define NE 160000
#define FD 64
#define BN (NB * NN)              // 80000
#define TOTE (NB * NE)            // 1280000
#define LB_PER_G 78               // linear blocks per graph (78*16 waves = 1248)
#define WPG 1248                  // waves per graph in persistent kernels
#define AB_PER_G 312              // agg blocks per graph (312*4 waves = 1248)

// ============ dispatch 1: fused CSR build (blocks 0..7) + linear1 (blocks 8+) ============
// Build: one block per graph. Per-graph LDS histogram -> in-block scan -> fill
// with LDS cursors. Cross-graph CSR offsets are static (g*NE) since every
// graph has exactly NE edges. Zero global atomics.
// Linear1: lane j holds W1 row j in 64 VGPRs; h broadcast via const-lane
// __shfl (v_readlane). No LDS at all on this path.
__global__ __launch_bounds__(1024) void k_build_lin(const int* __restrict__ ei,
                                                    const float* __restrict__ x,
                                                    const float* __restrict__ W1,
                                                    const float* __restrict__ b1,
                                                    int2* __restrict__ edge_cn,
                                                    int* __restrict__ row_start,
                                                    float* __restrict__ dinv,
                                                    float* __restrict__ t1) {
    __shared__ int hist[NN];      // 40 KB
    __shared__ int wsums[16];
    __shared__ int carry_s;

    if (blockIdx.x < 8) {
        // ---------------- build path ----------------
        const int g = blockIdx.x;
        const int tid = threadIdx.x;
        const int lane = tid & 63;
        const int wv = tid >> 6;
        for (int i = tid; i < NN; i += 1024) hist[i] = 0;
        if (tid == 0) carry_s = 0;
        __syncthreads();

        const int2* eg = (const int2*)ei + (size_t)g * NE;
        // phase 1: histogram (LDS atomics)
        for (int i = tid; i < NE; i += 1024) {
            int2 e = eg[i];
            atomicAdd(&hist[e.x], 1);
        }
        __syncthreads();

        // phase 2: in-block exclusive scan of hist -> prefix (in place),
        // write row_start + dinv (global, tiny & L2-hot)
        for (int base = 0; base < NN; base += 1024) {
            int i = base + tid;
            int v = (i < NN) ? hist[i] : 0;
            int xx = v;
#pragma unroll
            for (int off = 1; off < 64; off <<= 1) {
                int y = __shfl_up(xx, off);
                if (lane >= off) xx += y;
            }
            if (lane == 63) wsums[wv] = xx;
            __syncthreads();
            if (wv == 0 && lane < 16) {
                int s = wsums[lane];
#pragma unroll
                for (int off = 1; off < 16; off <<= 1) {
                    int y = __shfl_up(s, off, 16);
                    if (lane >= off) s += y;
                }
                wsums[lane] = s;
            }
            __syncthreads();
            int excl = carry_s + ((wv > 0) ? wsums[wv - 1] : 0) + (xx - v);
            if (i < NN) {
                hist[i] = excl;                       // cursor base for fill
                row_start[g * NN + i] = g * NE + excl;
                dinv[g * NN + i] = (v > 0) ? (1.0f / sqrtf((float)v)) : 0.0f;
            }
            __syncthreads();
            if (tid == 0) carry_s += wsums[15];
            __syncthreads();
        }
        if (tid == 0 && g == 0) row_start[BN] = TOTE;

        // phase 3: fill (LDS cursor atomics give position directly)
        const float* dv = dinv + g * NN;
        for (int i = tid; i < NE; i += 1024) {
            int2 e = eg[i];
            int pos = atomicAdd(&hist[e.x], 1);
            float nm = dv[e.x] * dv[e.y];
            edge_cn[(size_t)g * NE + pos] = make_int2(g * NN + e.y, __float_as_int(nm));
        }
    } else {
        // ---------------- linear1 path: t1 = x @ W1^T + b1 ----------------
        int b = blockIdx.x - 8;
        int g = b & 7;
        int wb = b >> 3;                        // 0..77
        int wv = threadIdx.x >> 6;              // 0..15
        int j = threadIdx.x & 63;
        int wig = wb * 16 + wv;                 // 0..1247

        float4 wreg[16];
        const float4* wp = (const float4*)(W1 + j * FD);
#pragma unroll
        for (int q = 0; q < 16; q++) wreg[q] = wp[q];
        float bj = b1[j];

        for (int nl = wig; nl < NN; nl += WPG) {
            size_t n = (size_t)g * NN + nl;
            float h = x[n * FD + j];
            float tj = bj;
#pragma unroll
            for (int q = 0; q < 16; q++) {
                float4 w = wreg[q];
                tj += __shfl(h, 4 * q + 0) * w.x + __shfl(h, 4 * q + 1) * w.y +
                      __shfl(h, 4 * q + 2) * w.z + __shfl(h, 4 * q + 3) * w.w;
            }
            t1[n * FD + j] = tj;
        }
    }
}

// ============ fused aggregate (+ optional relu+linear of next layer) ============
// Persistent: 2496 blocks x 4 waves; wave handles nodes nl, nl+1248, ... of its
// graph. Gather: lane = eg(2b)*16 + fl(4b), 16 edges in flight. After the
// shuffle-reduce, lanes 0..15 hold h'[4fl..4fl+3]; LIN=1 then computes
// t_next[n][j] = relu(h')@W^T + b with register-held W row j per lane.
// XCD swizzle g = blk&7 keeps graph g's t slice (2.56 MB) in one XCD L2.
template <int LIN>
__global__ __launch_bounds__(256) void k_agg_lin(const float* __restrict__ t,
                                                 const int* __restrict__ row_start,
                                                 const int2* __restrict__ edge_cn,
                                                 const float* __restrict__ W,
                                                 const float* __restrict__ bias,
                                                 float* __restrict__ outp) {
    int g = blockIdx.x & 7;
    int wb = blockIdx.x >> 3;                   // 0..311
    int wv = threadIdx.x >> 6;                  // 0..3
    int lane = threadIdx.x & 63;
    int wig = wb * 4 + wv;                      // 0..1247
    int eg = lane >> 4;
    int fl = lane & 15;

    float4 wreg[16];
    float bj = 0.f;
    if (LIN) {
        const float4* wp = (const float4*)(W + lane * FD);
#pragma unroll
        for (int q = 0; q < 16; q++) wreg[q] = wp[q];
        bj = bias[lane];
    }

    for (int nl = wig; nl < NN; nl += WPG) {
        int node = g * NN + nl;
        int p0 = row_start[node];
        int pe = row_start[node + 1];
        float4 acc = make_float4(0.f, 0.f, 0.f, 0.f);
        int p = p0 + eg;
        for (; p + 12 < pe; p += 16) {
            int2 cn0 = edge_cn[p];
            int2 cn1 = edge_cn[p + 4];
            int2 cn2 = edge_cn[p + 8];
            int2 cn3 = edge_cn[p + 12];
            float4 t0 = ((const float4*)(t + (size_t)cn0.x * FD))[fl];
            float4 t1v = ((const float4*)(t + (size_t)cn1.x * FD))[fl];
            float4 t2v = ((const float4*)(t + (size_t)cn2.x * FD))[fl];
            float4 t3v = ((const float4*)(t + (size_t)cn3.x * FD))[fl];
            float n0 = __int_as_float(cn0.y), n1 = __int_as_float(cn1.y);
            float n2 = __int_as_float(cn2.y), n3 = __int_as_float(cn3.y);
            acc.x += n0 * t0.x + n1 * t1v.x + n2 * t2v.x + n3 * t3v.x;
            acc.y += n0 * t0.y + n1 * t1v.y + n2 * t2v.y + n3 * t3v.y;
            acc.z += n0 * t0.z + n1 * t1v.z + n2 * t2v.z + n3 * t3v.z;
            acc.w += n0 * t0.w + n1 * t1v.w + n2 * t2v.w + n3 * t3v.w;
        }
        for (; p < pe; p += 4) {
            int2 cn = edge_cn[p];
            float4 tv = ((const float4*)(t + (size_t)cn.x * FD))[fl];
            float nm = __int_as_float(cn.y);
            acc.x += nm * tv.x;
            acc.y += nm * tv.y;
            acc.z += nm * tv.z;
            acc.w += nm * tv.w;
        }
        acc.x += __shfl_down(acc.x, 32); acc.y += __shfl_down(acc.y, 32);
        acc.z += __shfl_down(acc.z, 32); acc.w += __shfl_down(acc.w, 32);
        acc.x += __shfl_down(acc.x, 16); acc.y += __shfl_down(acc.y, 16);
        acc.z += __shfl_down(acc.z, 16); acc.w += __shfl_down(acc.w, 16);

        if (LIN) {
            // lanes 0..15 hold h'[4fl..4fl+3]; apply relu there, broadcast via
            // const-lane shuffles, every lane j computes t_next[node][j].
            float4 hv = acc;
            hv.x = fmaxf(hv.x, 0.f); hv.y = fmaxf(hv.y, 0.f);
            hv.z = fmaxf(hv.z, 0.f); hv.w = fmaxf(hv.w, 0.f);
            float tj = bj;
#pragma unroll
            for (int q = 0; q < 16; q++) {
                float4 w = wreg[q];
                tj += __shfl(hv.x, q) * w.x + __shfl(hv.y, q) * w.y +
                      __shfl(hv.z, q) * w.z + __shfl(hv.w, q) * w.w;
            }
            outp[(size_t)node * FD + lane] = tj;
        } else {
            if (lane < 16) {
                float4* op = (float4*)(outp + (size_t)node * FD);
                op[fl] = acc;
            }
        }
    }
}

extern "C" void kernel_launch(void* const* d_in, const int* in_sizes, int n_in,
                              void* d_out, int out_size, void* d_ws, size_t ws_size,
                              hipStream_t stream) {
    const float* x  = (const float*)d_in[0];
    const int*   ei = (const int*)d_in[1];
    const float* W1 = (const float*)d_in[2];
    const float* b1 = (const float*)d_in[3];
    const float* W2 = (const float*)d_in[4];
    const float* b2 = (const float*)d_in[5];
    const float* W3 = (const float*)d_in[6];
    const float* b3 = (const float*)d_in[7];
    float* out = (float*)d_out;

    char* ws = (char*)d_ws;
    size_t off = 0;
    float* t1       = (float*)(ws + off); off += (size_t)BN * FD * 4;     // 20.48 MB
    float* t2       = (float*)(ws + off); off += (size_t)BN * FD * 4;     // 20.48 MB
    int2*  edge_cn  = (int2*)(ws + off);  off += (size_t)TOTE * 8;        // 10.24 MB
    int*   row_start= (int*)(ws + off);   off += (size_t)(BN + 1) * 4;
    float* dinv     = (float*)(ws + off); off += (size_t)BN * 4;

    const int bb = 8 + NB * LB_PER_G;       // 8 build + 624 linear blocks
    const int ab = NB * AB_PER_G;           // 2496

    // 1: CSR build + t1 = x@W1^T+b1 (independent halves, one dispatch)
    k_build_lin<<<bb, 1024, 0, stream>>>(ei, x, W1, b1, edge_cn, row_start, dinv, t1);
    // 2: h1 = agg(t1); t2 = relu(h1)@W2^T + b2
    k_agg_lin<1><<<ab, 256, 0, stream>>>(t1, row_start, edge_cn, W2, b2, t2);
    // 3: h2 = agg(t2); t1 = relu(h2)@W3^T + b3
    k_agg_lin<1><<<ab, 256, 0, stream>>>(t2, row_start, edge_cn, W3, b3, t1);
    // 4: out = agg(t1)
    k_agg_lin<0><<<ab, 256, 0, stream>>>(t1, row_start, edge_cn, nullptr, nullptr, out);
}

// Round 7
// 398.256 us; speedup vs baseline: 1.6742x; 1.6742x over previous
//
#include <hip/hip_runtime.h>
#include <math.h>

#define NB 8
#define NN 10000
#define NE 160000
#define FD 64
#define BN (NB * NN)              // 80000
#define TOTE (NB * NE)            // 1280000
#define EPB 10000                 // edges per count chunk
#define BPG (NE / EPB)            // 16 chunks per graph
#define NPA (NB * BPG)            // 128 count blocks
#define FILLB 5000                // fill blocks (5000*256 = TOTE exact)
#define LINB 320                  // linear blocks (40 per graph)

// ---------- 1: LDS histogram count + per-edge local rank (128 blocks) ----------
__global__ __launch_bounds__(256) void k_count_lds(const int* __restrict__ ei,
                                                   int* __restrict__ rank,
                                                   int* __restrict__ cnt) {
    __shared__ int hist[NN];  // 40 KB
    for (int i = threadIdx.x; i < NN; i += 256) hist[i] = 0;
    __syncthreads();
    int g = blockIdx.x >> 4;
    int j = blockIdx.x & 15;
    int base = g * NE + j * EPB;
    for (int i = threadIdx.x; i < EPB; i += 256) {
        int e = base + i;
        int r = ei[2 * e];
        rank[e] = atomicAdd(&hist[r], 1);
    }
    __syncthreads();
    int* cp = cnt + (size_t)blockIdx.x * NN;
    for (int i = threadIdx.x; i < NN; i += 256) cp[i] = hist[i];
}

// ---------- 2: per-graph scan (8 blocks x 1024) ----------
// Cross-graph offsets are static (g*NE), so only a within-graph scan over
// 10000 rows is needed. Also converts cnt to per-chunk exclusive offsets
// and writes dinv. Work = 0.64 MB/graph -> ~10 us despite 8 blocks.
__global__ __launch_bounds__(1024) void k_scan_g(int* __restrict__ cnt,
                                                 int* __restrict__ row_start,
                                                 float* __restrict__ dinv) {
    __shared__ int wsums[16];
    __shared__ int carry_s;
    const int g = blockIdx.x;
    const int tid = threadIdx.x;
    const int lane = tid & 63;
    const int wv = tid >> 6;
    if (tid == 0) carry_s = 0;
    if (g == 0 && tid == 0) row_start[BN] = TOTE;
    __syncthreads();
    for (int base = 0; base < NN; base += 1024) {
        int i = base + tid;
        int d = 0;
        if (i < NN) {
            int* cp = cnt + ((size_t)g * BPG) * NN + i;
            int run = 0;
#pragma unroll
            for (int j = 0; j < BPG; j++) {
                int v = cp[(size_t)j * NN];
                cp[(size_t)j * NN] = run;   // exclusive prefix across chunks
                run += v;
            }
            d = run;
        }
        int x = d;
#pragma unroll
        for (int off = 1; off < 64; off <<= 1) {
            int y = __shfl_up(x, off);
            if (lane >= off) x += y;
        }
        if (lane == 63) wsums[wv] = x;
        __syncthreads();
        if (wv == 0 && lane < 16) {
            int s = wsums[lane];
#pragma unroll
            for (int off = 1; off < 16; off <<= 1) {
                int y = __shfl_up(s, off, 16);
                if (lane >= off) s += y;
            }
            wsums[lane] = s;
        }
        __syncthreads();
        int excl = carry_s + ((wv > 0) ? wsums[wv - 1] : 0) + (x - d);
        if (i < NN) {
            row_start[g * NN + i] = g * NE + excl;
            dinv[g * NN + i] = (d > 0) ? (1.0f / sqrtf((float)d)) : 0.0f;
        }
        __syncthreads();
        if (tid == 0) carry_s += wsums[15];
        __syncthreads();
    }
}

// ---------- 3: fill CSR (blocks 0..4999) + linear1 (blocks 5000..5319) ----------
__global__ __launch_bounds__(256) void k_fill_lin(const int* __restrict__ ei,
                                                  const int* __restrict__ row_start,
                                                  const int* __restrict__ rank,
                                                  const int* __restrict__ cnt,
                                                  const float* __restrict__ dinv,
                                                  int2* __restrict__ edge_cn,
                                                  const float* __restrict__ x,
                                                  const float* __restrict__ W1,
                                                  const float* __restrict__ b1,
                                                  float* __restrict__ t1) {
    __shared__ __align__(16) float Wt[FD * FD];
    __shared__ float bsh[FD];
    if (blockIdx.x < FILLB) {
        // ---- fill path (XCD swizzle: g = blk&7) ----
        int g = blockIdx.x & 7;
        int j = blockIdx.x >> 3;
        int idx = j * 256 + threadIdx.x;
        int e = g * NE + idx;
        int jj = idx / EPB;
        int rl = ei[2 * e];
        int cl = ei[2 * e + 1];
        int r = g * NN + rl;
        int c = g * NN + cl;
        int pos = row_start[r] + cnt[((size_t)(g * BPG + jj)) * NN + rl] + rank[e];
        float nm = dinv[r] * dinv[c];
        edge_cn[pos] = make_int2(c, __float_as_int(nm));
    } else {
        // ---- linear1 path: t1 = x @ W1^T + b1 (R5-proven structure) ----
        for (int idx = threadIdx.x; idx < FD * FD; idx += 256) {
            int j = idx >> 6, k = idx & 63;
            Wt[k * FD + j] = W1[idx];
        }
        if (threadIdx.x < FD) bsh[threadIdx.x] = b1[threadIdx.x];
        __syncthreads();

        int b = blockIdx.x - FILLB;
        int g = b & 7;
        int i = b >> 3;                          // 0..39
        int nl = i * 256 + (int)threadIdx.x;
        if (nl >= NN) return;
        int n = g * NN + nl;

        float acc[FD];
#pragma unroll
        for (int j = 0; j < FD; j++) acc[j] = bsh[j];

        const float4* hp = (const float4*)(x + (size_t)n * FD);
#pragma unroll
        for (int k4 = 0; k4 < 16; k4++) {
            float4 hv = hp[k4];
            float hk[4] = {hv.x, hv.y, hv.z, hv.w};
#pragma unroll
            for (int kk = 0; kk < 4; kk++) {
                const float4* wr = (const float4*)(&Wt[(k4 * 4 + kk) * FD]);
                float h = hk[kk];
#pragma unroll
                for (int j4 = 0; j4 < 16; j4++) {
                    float4 w = wr[j4];
                    acc[4 * j4 + 0] += h * w.x;
                    acc[4 * j4 + 1] += h * w.y;
                    acc[4 * j4 + 2] += h * w.z;
                    acc[4 * j4 + 3] += h * w.w;
                }
            }
        }
        float4* op = (float4*)(t1 + (size_t)n * FD);
#pragma unroll
        for (int j4 = 0; j4 < 16; j4++)
            op[j4] = make_float4(acc[4 * j4], acc[4 * j4 + 1], acc[4 * j4 + 2], acc[4 * j4 + 3]);
    }
}

// ---------- 4-6: fused aggregate (+ optional relu+linear) ----------
// 5000 blocks x 4 waves = 20000 waves, 4 nodes/wave (stride 2500).
// Gather: lane = eg(2b)*16 + fl(4b), 16 edges in flight. After shuffle-reduce,
// lanes 0..15 hold h'[4fl..]; LIN=1 computes t_next[n][j] with register-held
// W row j (correctness verified in R6). XCD swizzle g = blk&7.
template <int LIN>
__global__ __launch_bounds__(256, 4) void k_agg_lin(const float* __restrict__ t,
                                                    const int* __restrict__ row_start,
                                                    const int2* __restrict__ edge_cn,
                                                    const float* __restrict__ W,
                                                    const float* __restrict__ bias,
                                                    float* __restrict__ outp) {
    int g = blockIdx.x & 7;
    int wb = blockIdx.x >> 3;                   // 0..624
    int wv = threadIdx.x >> 6;
    int lane = threadIdx.x & 63;
    int wig = wb * 4 + wv;                      // 0..2499
    int eg = lane >> 4;
    int fl = lane & 15;

    float4 wreg[16];
    float bj = 0.f;
    if (LIN) {
        const float4* wp = (const float4*)(W + lane * FD);
#pragma unroll
        for (int q = 0; q < 16; q++) wreg[q] = wp[q];
        bj = bias[lane];
    }

    for (int s = 0; s < 4; s++) {
        int nl = wig + s * 2500;
        int node = g * NN + nl;
        int p0 = row_start[node];
        int pe = row_start[node + 1];
        float4 acc = make_float4(0.f, 0.f, 0.f, 0.f);
        int p = p0 + eg;
        for (; p + 12 < pe; p += 16) {
            int2 cn0 = edge_cn[p];
            int2 cn1 = edge_cn[p + 4];
            int2 cn2 = edge_cn[p + 8];
            int2 cn3 = edge_cn[p + 12];
            float4 t0 = ((const float4*)(t + (size_t)cn0.x * FD))[fl];
            float4 t1v = ((const float4*)(t + (size_t)cn1.x * FD))[fl];
            float4 t2v = ((const float4*)(t + (size_t)cn2.x * FD))[fl];
            float4 t3v = ((const float4*)(t + (size_t)cn3.x * FD))[fl];
            float n0 = __int_as_float(cn0.y), n1 = __int_as_float(cn1.y);
            float n2 = __int_as_float(cn2.y), n3 = __int_as_float(cn3.y);
            acc.x += n0 * t0.x + n1 * t1v.x + n2 * t2v.x + n3 * t3v.x;
            acc.y += n0 * t0.y + n1 * t1v.y + n2 * t2v.y + n3 * t3v.y;
            acc.z += n0 * t0.z + n1 * t1v.z + n2 * t2v.z + n3 * t3v.z;
            acc.w += n0 * t0.w + n1 * t1v.w + n2 * t2v.w + n3 * t3v.w;
        }
        for (; p < pe; p += 4) {
            int2 cn = edge_cn[p];
            float4 tv = ((const float4*)(t + (size_t)cn.x * FD))[fl];
            float nm = __int_as_float(cn.y);
            acc.x += nm * tv.x;
            acc.y += nm * tv.y;
            acc.z += nm * tv.z;
            acc.w += nm * tv.w;
        }
        acc.x += __shfl_down(acc.x, 32); acc.y += __shfl_down(acc.y, 32);
        acc.z += __shfl_down(acc.z, 32); acc.w += __shfl_down(acc.w, 32);
        acc.x += __shfl_down(acc.x, 16); acc.y += __shfl_down(acc.y, 16);
        acc.z += __shfl_down(acc.z, 16); acc.w += __shfl_down(acc.w, 16);

        if (LIN) {
            float4 hv = acc;
            hv.x = fmaxf(hv.x, 0.f); hv.y = fmaxf(hv.y, 0.f);
            hv.z = fmaxf(hv.z, 0.f); hv.w = fmaxf(hv.w, 0.f);
            float tj = bj;
#pragma unroll
            for (int q = 0; q < 16; q++) {
                float4 w = wreg[q];
                tj += __shfl(hv.x, q) * w.x + __shfl(hv.y, q) * w.y +
                      __shfl(hv.z, q) * w.z + __shfl(hv.w, q) * w.w;
            }
            outp[(size_t)node * FD + lane] = tj;
        } else {
            if (lane < 16) {
                float4* op = (float4*)(outp + (size_t)node * FD);
                op[fl] = acc;
            }
        }
    }
}

extern "C" void kernel_launch(void* const* d_in, const int* in_sizes, int n_in,
                              void* d_out, int out_size, void* d_ws, size_t ws_size,
                              hipStream_t stream) {
    const float* x  = (const float*)d_in[0];
    const int*   ei = (const int*)d_in[1];
    const float* W1 = (const float*)d_in[2];
    const float* b1 = (const float*)d_in[3];
    const float* W2 = (const float*)d_in[4];
    const float* b2 = (const float*)d_in[5];
    const float* W3 = (const float*)d_in[6];
    const float* b3 = (const float*)d_in[7];
    float* out = (float*)d_out;

    char* ws = (char*)d_ws;
    size_t off = 0;
    float* t1       = (float*)(ws + off); off += (size_t)BN * FD * 4;     // 20.48 MB
    float* t2       = (float*)(ws + off); off += (size_t)BN * FD * 4;     // 20.48 MB
    int2*  edge_cn  = (int2*)(ws + off);  off += (size_t)TOTE * 8;        // 10.24 MB
    int*   row_start= (int*)(ws + off);   off += (size_t)(BN + 1) * 4;
    float* dinv     = (float*)(ws + off); off += (size_t)BN * 4;
    // rank (5.12 MB) + cnt (5.12 MB) alias t2: dead before dispatch 4 writes t2.
    // (NOT t1 — t1 is written by lin1 in the same dispatch that reads rank/cnt.)
    int*   rank     = (int*)t2;
    int*   cnt      = (int*)t2 + (size_t)TOTE;

    k_count_lds<<<NPA, 256, 0, stream>>>(ei, rank, cnt);
    k_scan_g<<<NB, 1024, 0, stream>>>(cnt, row_start, dinv);
    k_fill_lin<<<FILLB + LINB, 256, 0, stream>>>(ei, row_start, rank, cnt, dinv,
                                                 edge_cn, x, W1, b1, t1);
    // h1 = agg(t1); t2 = relu(h1)@W2^T + b2
    k_agg_lin<1><<<FILLB, 256, 0, stream>>>(t1, row_start, edge_cn, W2, b2, t2);
    // h2 = agg(t2); t1 = relu(h2)@W3^T + b3
    k_agg_lin<1><<<FILLB, 256, 0, stream>>>(t2, row_start, edge_cn, W3, b3, t1);
    // out = agg(t1)
    k_agg_lin<0><<<FILLB, 256, 0, stream>>>(t1, row_start, edge_cn, nullptr, nullptr, out);
}

// Round 8
// 330.177 us; speedup vs baseline: 2.0194x; 1.2062x over previous
//
#include <hip/hip_runtime.h>
#include <math.h>

#define NB 8
#define NN 10000
#define NE 160000
#define FD 64
#define BN (NB * NN)              // 80000
#define TOTE (NB * NE)            // 1280000
#define EPB 10000                 // edges per count chunk
#define BPG (NE / EPB)            // 16 chunks per graph
#define NPA (NB * BPG)            // 128 count blocks
#define FILLB 5000                // fill blocks (5000*256 = TOTE exact)
#define LINB 320                  // linear blocks (40 per graph)

// ---------- 1: LDS histogram count + per-edge local rank (128 blocks) ----------
__global__ __launch_bounds__(256) void k_count_lds(const int* __restrict__ ei,
                                                   int* __restrict__ rank,
                                                   int* __restrict__ cnt) {
    __shared__ int hist[NN];  // 40 KB
    for (int i = threadIdx.x; i < NN; i += 256) hist[i] = 0;
    __syncthreads();
    int g = blockIdx.x >> 4;
    int j = blockIdx.x & 15;
    int base = g * NE + j * EPB;
    for (int i = threadIdx.x; i < EPB; i += 256) {
        int e = base + i;
        int r = ei[2 * e];
        rank[e] = atomicAdd(&hist[r], 1);
    }
    __syncthreads();
    int* cp = cnt + (size_t)blockIdx.x * NN;
    for (int i = threadIdx.x; i < NN; i += 256) cp[i] = hist[i];
}

// ---------- 2: per-graph scan (8 blocks x 1024) ----------
// Cross-graph offsets static (g*NE); within-graph scan over 10000 rows.
// Converts cnt to per-chunk exclusive offsets, writes row_start + dinv.
__global__ __launch_bounds__(1024) void k_scan_g(int* __restrict__ cnt,
                                                 int* __restrict__ row_start,
                                                 float* __restrict__ dinv) {
    __shared__ int wsums[16];
    __shared__ int carry_s;
    const int g = blockIdx.x;
    const int tid = threadIdx.x;
    const int lane = tid & 63;
    const int wv = tid >> 6;
    if (tid == 0) carry_s = 0;
    if (g == 0 && tid == 0) row_start[BN] = TOTE;
    __syncthreads();
    for (int base = 0; base < NN; base += 1024) {
        int i = base + tid;
        int d = 0;
        if (i < NN) {
            int* cp = cnt + ((size_t)g * BPG) * NN + i;
            int run = 0;
#pragma unroll
            for (int j = 0; j < BPG; j++) {
                int v = cp[(size_t)j * NN];
                cp[(size_t)j * NN] = run;
                run += v;
            }
            d = run;
        }
        int x = d;
#pragma unroll
        for (int off = 1; off < 64; off <<= 1) {
            int y = __shfl_up(x, off);
            if (lane >= off) x += y;
        }
        if (lane == 63) wsums[wv] = x;
        __syncthreads();
        if (wv == 0 && lane < 16) {
            int s = wsums[lane];
#pragma unroll
            for (int off = 1; off < 16; off <<= 1) {
                int y = __shfl_up(s, off, 16);
                if (lane >= off) s += y;
            }
            wsums[lane] = s;
        }
        __syncthreads();
        int excl = carry_s + ((wv > 0) ? wsums[wv - 1] : 0) + (x - d);
        if (i < NN) {
            row_start[g * NN + i] = g * NE + excl;
            dinv[g * NN + i] = (d > 0) ? (1.0f / sqrtf((float)d)) : 0.0f;
        }
        __syncthreads();
        if (tid == 0) carry_s += wsums[15];
        __syncthreads();
    }
}

// ---------- 3: fill CSR (blocks 0..4999) + linear1 (blocks 5000..5319) ----------
__global__ __launch_bounds__(256) void k_fill_lin(const int* __restrict__ ei,
                                                  const int* __restrict__ row_start,
                                                  const int* __restrict__ rank,
                                                  const int* __restrict__ cnt,
                                                  const float* __restrict__ dinv,
                                                  int2* __restrict__ edge_cn,
                                                  const float* __restrict__ x,
                                                  const float* __restrict__ W1,
                                                  const float* __restrict__ b1,
                                                  float* __restrict__ t1) {
    __shared__ __align__(16) float Wt[FD * FD];
    __shared__ float bsh[FD];
    if (blockIdx.x < FILLB) {
        // ---- fill path (XCD swizzle: g = blk&7) ----
        int g = blockIdx.x & 7;
        int j = blockIdx.x >> 3;
        int idx = j * 256 + threadIdx.x;
        int e = g * NE + idx;
        int jj = idx / EPB;
        int rl = ei[2 * e];
        int cl = ei[2 * e + 1];
        int r = g * NN + rl;
        int c = g * NN + cl;
        int pos = row_start[r] + cnt[((size_t)(g * BPG + jj)) * NN + rl] + rank[e];
        float nm = dinv[r] * dinv[c];
        edge_cn[pos] = make_int2(c, __float_as_int(nm));
    } else {
        // ---- linear1: t1 = x @ W1^T + b1 (R5-proven LDS-broadcast form) ----
        for (int idx = threadIdx.x; idx < FD * FD; idx += 256) {
            int j = idx >> 6, k = idx & 63;
            Wt[k * FD + j] = W1[idx];
        }
        if (threadIdx.x < FD) bsh[threadIdx.x] = b1[threadIdx.x];
        __syncthreads();

        int b = blockIdx.x - FILLB;
        int g = b & 7;
        int i = b >> 3;
        int nl = i * 256 + (int)threadIdx.x;
        if (nl >= NN) return;
        int n = g * NN + nl;

        float acc[FD];
#pragma unroll
        for (int j = 0; j < FD; j++) acc[j] = bsh[j];

        const float4* hp = (const float4*)(x + (size_t)n * FD);
#pragma unroll
        for (int k4 = 0; k4 < 16; k4++) {
            float4 hv = hp[k4];
            float hk[4] = {hv.x, hv.y, hv.z, hv.w};
#pragma unroll
            for (int kk = 0; kk < 4; kk++) {
                const float4* wr = (const float4*)(&Wt[(k4 * 4 + kk) * FD]);
                float h = hk[kk];
#pragma unroll
                for (int j4 = 0; j4 < 16; j4++) {
                    float4 w = wr[j4];
                    acc[4 * j4 + 0] += h * w.x;
                    acc[4 * j4 + 1] += h * w.y;
                    acc[4 * j4 + 2] += h * w.z;
                    acc[4 * j4 + 3] += h * w.w;
                }
            }
        }
        float4* op = (float4*)(t1 + (size_t)n * FD);
#pragma unroll
        for (int j4 = 0; j4 < 16; j4++)
            op[j4] = make_float4(acc[4 * j4], acc[4 * j4 + 1], acc[4 * j4 + 2], acc[4 * j4 + 3]);
    }
}

// ---------- linear (layers 2,3): t[n] = relu(h[n]) @ W^T + b ----------
__global__ __launch_bounds__(256) void k_linear(const float* __restrict__ hin,
                                                const float* __restrict__ W,
                                                const float* __restrict__ bias,
                                                float* __restrict__ tout) {
    __shared__ __align__(16) float Wt[FD * FD];
    __shared__ float bsh[FD];
    for (int idx = threadIdx.x; idx < FD * FD; idx += 256) {
        int j = idx >> 6, k = idx & 63;
        Wt[k * FD + j] = W[idx];
    }
    if (threadIdx.x < FD) bsh[threadIdx.x] = bias[threadIdx.x];
    __syncthreads();

    int b = blockIdx.x;
    int g = b & 7;
    int i = b >> 3;
    int nl = i * 256 + (int)threadIdx.x;
    if (nl >= NN) return;
    int n = g * NN + nl;

    float acc[FD];
#pragma unroll
    for (int j = 0; j < FD; j++) acc[j] = bsh[j];

    const float4* hp = (const float4*)(hin + (size_t)n * FD);
#pragma unroll
    for (int k4 = 0; k4 < 16; k4++) {
        float4 hv = hp[k4];
        hv.x = fmaxf(hv.x, 0.f);
        hv.y = fmaxf(hv.y, 0.f);
        hv.z = fmaxf(hv.z, 0.f);
        hv.w = fmaxf(hv.w, 0.f);
        float hk[4] = {hv.x, hv.y, hv.z, hv.w};
#pragma unroll
        for (int kk = 0; kk < 4; kk++) {
            const float4* wr = (const float4*)(&Wt[(k4 * 4 + kk) * FD]);
            float h = hk[kk];
#pragma unroll
            for (int j4 = 0; j4 < 16; j4++) {
                float4 w = wr[j4];
                acc[4 * j4 + 0] += h * w.x;
                acc[4 * j4 + 1] += h * w.y;
                acc[4 * j4 + 2] += h * w.z;
                acc[4 * j4 + 3] += h * w.w;
            }
        }
    }
    float4* op = (float4*)(tout + (size_t)n * FD);
#pragma unroll
    for (int j4 = 0; j4 < 16; j4++)
        op[j4] = make_float4(acc[4 * j4], acc[4 * j4 + 1], acc[4 * j4 + 2], acc[4 * j4 + 3]);
}

// ---------- aggregate (pull, CSR): one node per wave, 16 edges in flight ----------
// lane = eg(2b)*16 + fl(4b). XCD swizzle g = blk&7 keeps graph g's t slice
// (2.56 MB) in one XCD's 4 MB L2. (R5-proven, ~50 us/layer.)
__global__ __launch_bounds__(256) void k_agg(const float* __restrict__ t,
                                             const int* __restrict__ row_start,
                                             const int2* __restrict__ edge_cn,
                                             float* __restrict__ out) {
    int g = blockIdx.x & 7;
    int i = blockIdx.x >> 3;                          // 0..2499
    int node = g * NN + i * 4 + ((int)threadIdx.x >> 6);
    int lane = threadIdx.x & 63;
    int p0 = row_start[node];
    int pe = row_start[node + 1];
    int eg = lane >> 4;
    int fl = lane & 15;
    float4 acc = make_float4(0.f, 0.f, 0.f, 0.f);
    int p = p0 + eg;
    for (; p + 12 < pe; p += 16) {
        int2 cn0 = edge_cn[p];
        int2 cn1 = edge_cn[p + 4];
        int2 cn2 = edge_cn[p + 8];
        int2 cn3 = edge_cn[p + 12];
        float4 t0 = ((const float4*)(t + (size_t)cn0.x * FD))[fl];
        float4 t1v = ((const float4*)(t + (size_t)cn1.x * FD))[fl];
        float4 t2v = ((const float4*)(t + (size_t)cn2.x * FD))[fl];
        float4 t3v = ((const float4*)(t + (size_t)cn3.x * FD))[fl];
        float n0 = __int_as_float(cn0.y), n1 = __int_as_float(cn1.y);
        float n2 = __int_as_float(cn2.y), n3 = __int_as_float(cn3.y);
        acc.x += n0 * t0.x + n1 * t1v.x + n2 * t2v.x + n3 * t3v.x;
        acc.y += n0 * t0.y + n1 * t1v.y + n2 * t2v.y + n3 * t3v.y;
        acc.z += n0 * t0.z + n1 * t1v.z + n2 * t2v.z + n3 * t3v.z;
        acc.w += n0 * t0.w + n1 * t1v.w + n2 * t2v.w + n3 * t3v.w;
    }
    for (; p < pe; p += 4) {
        int2 cn = edge_cn[p];
        float4 tv = ((const float4*)(t + (size_t)cn.x * FD))[fl];
        float nm = __int_as_float(cn.y);
        acc.x += nm * tv.x;
        acc.y += nm * tv.y;
        acc.z += nm * tv.z;
        acc.w += nm * tv.w;
    }
    acc.x += __shfl_down(acc.x, 32); acc.y += __shfl_down(acc.y, 32);
    acc.z += __shfl_down(acc.z, 32); acc.w += __shfl_down(acc.w, 32);
    acc.x += __shfl_down(acc.x, 16); acc.y += __shfl_down(acc.y, 16);
    acc.z += __shfl_down(acc.z, 16); acc.w += __shfl_down(acc.w, 16);
    if (lane < 16) {
        float4* op = (float4*)(out + (size_t)node * FD);
        op[fl] = acc;
    }
}

extern "C" void kernel_launch(void* const* d_in, const int* in_sizes, int n_in,
                              void* d_out, int out_size, void* d_ws, size_t ws_size,
                              hipStream_t stream) {
    const float* x  = (const float*)d_in[0];
    const int*   ei = (const int*)d_in[1];
    const float* W1 = (const float*)d_in[2];
    const float* b1 = (const float*)d_in[3];
    const float* W2 = (const float*)d_in[4];
    const float* b2 = (const float*)d_in[5];
    const float* W3 = (const float*)d_in[6];
    const float* b3 = (const float*)d_in[7];
    float* out = (float*)d_out;

    char* ws = (char*)d_ws;
    size_t off = 0;
    float* A        = (float*)(ws + off); off += (size_t)BN * FD * 4;     // 20.48 MB
    float* Bb       = (float*)(ws + off); off += (size_t)BN * FD * 4;     // 20.48 MB
    int2*  edge_cn  = (int2*)(ws + off);  off += (size_t)TOTE * 8;        // 10.24 MB
    int*   row_start= (int*)(ws + off);   off += (size_t)(BN + 1) * 4;
    float* dinv     = (float*)(ws + off); off += (size_t)BN * 4;
    // rank (5.12 MB) + cnt (5.12 MB) alias B: B is first written by agg1,
    // which is stream-ordered after fill (the last reader of rank/cnt).
    int*   rank     = (int*)Bb;
    int*   cnt      = (int*)Bb + (size_t)TOTE;

    const int ab = NB * (NN / 4);           // 20000

    k_count_lds<<<NPA, 256, 0, stream>>>(ei, rank, cnt);
    k_scan_g<<<NB, 1024, 0, stream>>>(cnt, row_start, dinv);
    // A = x@W1^T + b1 (blocks 5000+); CSR fill (blocks 0..4999)
    k_fill_lin<<<FILLB + LINB, 256, 0, stream>>>(ei, row_start, rank, cnt, dinv,
                                                 edge_cn, x, W1, b1, A);
    k_agg<<<ab, 256, 0, stream>>>(A, row_start, edge_cn, Bb);      // B = h1
    k_linear<<<LINB, 256, 0, stream>>>(Bb, W2, b2, A);             // A = relu(h1)@W2^T+b2
    k_agg<<<ab, 256, 0, stream>>>(A, row_start, edge_cn, Bb);      // B = h2
    k_linear<<<LINB, 256, 0, stream>>>(Bb, W3, b3, A);             // A = relu(h2)@W3^T+b3
    k_agg<<<ab, 256, 0, stream>>>(A, row_start, edge_cn, out);     // out = h3
}

// Round 9
// 303.596 us; speedup vs baseline: 2.1962x; 1.0876x over previous
//
#include <hip/hip_runtime.h>
#include <math.h>

#define NB 8
#define NN 10000
#define NE 160000
#define FD 64
#define BN (NB * NN)              // 80000
#define TOTE (NB * NE)            // 1280000
#define EPB 10000                 // edges per count chunk
#define BPG (NE / EPB)            // 16 chunks per graph
#define NPA (NB * BPG)            // 128 count blocks
#define FILLB 5000                // fill blocks (5000*256 = TOTE exact)
#define LINB 320                  // linear blocks (40 per graph)
#define WTS 68                    // padded Wt stride (272 B: float4-aligned, 8-way not 64-way bank conflict)

// ---------- 1: LDS histogram count + per-edge local rank (128 blocks) ----------
__global__ __launch_bounds__(256) void k_count_lds(const int* __restrict__ ei,
                                                   int* __restrict__ rank,
                                                   int* __restrict__ cnt) {
    __shared__ int hist[NN];  // 40 KB
    for (int i = threadIdx.x; i < NN; i += 256) hist[i] = 0;
    __syncthreads();
    int g = blockIdx.x >> 4;
    int j = blockIdx.x & 15;
    int base = g * NE + j * EPB;
    for (int i = threadIdx.x; i < EPB; i += 256) {
        int e = base + i;
        int r = ei[2 * e];
        rank[e] = atomicAdd(&hist[r], 1);
    }
    __syncthreads();
    int* cp = cnt + (size_t)blockIdx.x * NN;
    for (int i = threadIdx.x; i < NN; i += 256) cp[i] = hist[i];
}

// ---------- 2: per-graph scan (8 blocks x 1024) ----------
__global__ __launch_bounds__(1024) void k_scan_g(int* __restrict__ cnt,
                                                 int* __restrict__ row_start,
                                                 float* __restrict__ dinv) {
    __shared__ int wsums[16];
    __shared__ int carry_s;
    const int g = blockIdx.x;
    const int tid = threadIdx.x;
    const int lane = tid & 63;
    const int wv = tid >> 6;
    if (tid == 0) carry_s = 0;
    if (g == 0 && tid == 0) row_start[BN] = TOTE;
    __syncthreads();
    for (int base = 0; base < NN; base += 1024) {
        int i = base + tid;
        int d = 0;
        if (i < NN) {
            int* cp = cnt + ((size_t)g * BPG) * NN + i;
            int run = 0;
#pragma unroll
            for (int j = 0; j < BPG; j++) {
                int v = cp[(size_t)j * NN];
                cp[(size_t)j * NN] = run;
                run += v;
            }
            d = run;
        }
        int x = d;
#pragma unroll
        for (int off = 1; off < 64; off <<= 1) {
            int y = __shfl_up(x, off);
            if (lane >= off) x += y;
        }
        if (lane == 63) wsums[wv] = x;
        __syncthreads();
        if (wv == 0 && lane < 16) {
            int s = wsums[lane];
#pragma unroll
            for (int off = 1; off < 16; off <<= 1) {
                int y = __shfl_up(s, off, 16);
                if (lane >= off) s += y;
            }
            wsums[lane] = s;
        }
        __syncthreads();
        int excl = carry_s + ((wv > 0) ? wsums[wv - 1] : 0) + (x - d);
        if (i < NN) {
            row_start[g * NN + i] = g * NE + excl;
            dinv[g * NN + i] = (d > 0) ? (1.0f / sqrtf((float)d)) : 0.0f;
        }
        __syncthreads();
        if (tid == 0) carry_s += wsums[15];
        __syncthreads();
    }
}

// ---------- 3: fill CSR col-only (blocks 0..4999) + linear1 (blocks 5000..5319) ----------
// norm eliminated: agg uses dinv-scaled t rows, so fill writes only the col id.
__global__ __launch_bounds__(256) void k_fill_lin(const int* __restrict__ ei,
                                                  const int* __restrict__ row_start,
                                                  const int* __restrict__ rank,
                                                  const int* __restrict__ cnt,
                                                  int* __restrict__ edge_col,
                                                  const float* __restrict__ x,
                                                  const float* __restrict__ W1,
                                                  const float* __restrict__ b1,
                                                  const float* __restrict__ dinv,
                                                  float* __restrict__ t1) {
    __shared__ __align__(16) float Wt[WTS * FD];
    __shared__ float bsh[FD];
    if (blockIdx.x < FILLB) {
        // ---- fill path (XCD swizzle: g = blk&7) ----
        int g = blockIdx.x & 7;
        int j = blockIdx.x >> 3;
        int idx = j * 256 + threadIdx.x;
        int e = g * NE + idx;
        int jj = idx / EPB;
        int rl = ei[2 * e];
        int cl = ei[2 * e + 1];
        int r = g * NN + rl;
        int pos = row_start[r] + cnt[((size_t)(g * BPG + jj)) * NN + rl] + rank[e];
        edge_col[pos] = g * NN + cl;
    } else {
        // ---- linear1: t1 = dinv[n] * (x @ W1^T + b1) ----
        for (int idx = threadIdx.x; idx < FD * FD; idx += 256) {
            int j = idx >> 6, k = idx & 63;
            Wt[k * WTS + j] = W1[idx];
        }
        if (threadIdx.x < FD) bsh[threadIdx.x] = b1[threadIdx.x];
        __syncthreads();

        int b = blockIdx.x - FILLB;
        int g = b & 7;
        int i = b >> 3;
        int nl = i * 256 + (int)threadIdx.x;
        if (nl >= NN) return;
        int n = g * NN + nl;

        float acc[FD];
#pragma unroll
        for (int j = 0; j < FD; j++) acc[j] = bsh[j];

        const float4* hp = (const float4*)(x + (size_t)n * FD);
#pragma unroll
        for (int k4 = 0; k4 < 16; k4++) {
            float4 hv = hp[k4];
            float hk[4] = {hv.x, hv.y, hv.z, hv.w};
#pragma unroll
            for (int kk = 0; kk < 4; kk++) {
                const float4* wr = (const float4*)(&Wt[(k4 * 4 + kk) * WTS]);
                float h = hk[kk];
#pragma unroll
                for (int j4 = 0; j4 < 16; j4++) {
                    float4 w = wr[j4];
                    acc[4 * j4 + 0] += h * w.x;
                    acc[4 * j4 + 1] += h * w.y;
                    acc[4 * j4 + 2] += h * w.z;
                    acc[4 * j4 + 3] += h * w.w;
                }
            }
        }
        float dn = dinv[n];
        float4* op = (float4*)(t1 + (size_t)n * FD);
#pragma unroll
        for (int j4 = 0; j4 < 16; j4++)
            op[j4] = make_float4(dn * acc[4 * j4], dn * acc[4 * j4 + 1],
                                 dn * acc[4 * j4 + 2], dn * acc[4 * j4 + 3]);
    }
}

// ---------- linear (layers 2,3): t[n] = dinv[n] * (relu(h[n]) @ W^T + b) ----------
__global__ __launch_bounds__(256) void k_linear(const float* __restrict__ hin,
                                                const float* __restrict__ W,
                                                const float* __restrict__ bias,
                                                const float* __restrict__ dinv,
                                                float* __restrict__ tout) {
    __shared__ __align__(16) float Wt[WTS * FD];
    __shared__ float bsh[FD];
    for (int idx = threadIdx.x; idx < FD * FD; idx += 256) {
        int j = idx >> 6, k = idx & 63;
        Wt[k * WTS + j] = W[idx];
    }
    if (threadIdx.x < FD) bsh[threadIdx.x] = bias[threadIdx.x];
    __syncthreads();

    int b = blockIdx.x;
    int g = b & 7;
    int i = b >> 3;
    int nl = i * 256 + (int)threadIdx.x;
    if (nl >= NN) return;
    int n = g * NN + nl;

    float acc[FD];
#pragma unroll
    for (int j = 0; j < FD; j++) acc[j] = bsh[j];

    const float4* hp = (const float4*)(hin + (size_t)n * FD);
#pragma unroll
    for (int k4 = 0; k4 < 16; k4++) {
        float4 hv = hp[k4];
        hv.x = fmaxf(hv.x, 0.f);
        hv.y = fmaxf(hv.y, 0.f);
        hv.z = fmaxf(hv.z, 0.f);
        hv.w = fmaxf(hv.w, 0.f);
        float hk[4] = {hv.x, hv.y, hv.z, hv.w};
#pragma unroll
        for (int kk = 0; kk < 4; kk++) {
            const float4* wr = (const float4*)(&Wt[(k4 * 4 + kk) * WTS]);
            float h = hk[kk];
#pragma unroll
            for (int j4 = 0; j4 < 16; j4++) {
                float4 w = wr[j4];
                acc[4 * j4 + 0] += h * w.x;
                acc[4 * j4 + 1] += h * w.y;
                acc[4 * j4 + 2] += h * w.z;
                acc[4 * j4 + 3] += h * w.w;
            }
        }
    }
    float dn = dinv[n];
    float4* op = (float4*)(tout + (size_t)n * FD);
#pragma unroll
    for (int j4 = 0; j4 < 16; j4++)
        op[j4] = make_float4(dn * acc[4 * j4], dn * acc[4 * j4 + 1],
                             dn * acc[4 * j4 + 2], dn * acc[4 * j4 + 3]);
}

// ---------- aggregate: out[r] = dinv[r] * sum_e t[col[e]]  (t pre-scaled by dinv) ----------
// One node per wave. Superchunk: one coalesced load grabs <=64 edge cols
// (only deg lanes active), shfl-broadcast feeds the gathers. row_start/dinv
// via readfirstlane -> s_load (0 TA addresses). Tail gathers exec-masked.
// TA budget/wave (deg 16): ~16 meta + 256 gather + 16 store ~= 290 addr
// vs R8's ~832 -> predict ~2.5x faster.
__global__ __launch_bounds__(256) void k_agg(const float* __restrict__ t,
                                             const int* __restrict__ row_start,
                                             const int* __restrict__ edge_col,
                                             const float* __restrict__ dinv,
                                             float* __restrict__ out) {
    int g = blockIdx.x & 7;
    int i = blockIdx.x >> 3;                          // 0..2499
    int lane = threadIdx.x & 63;
    int node = __builtin_amdgcn_readfirstlane(g * NN + i * 4 + ((int)threadIdx.x >> 6));
    int p0 = row_start[node];
    int pe = row_start[node + 1];
    float dr = dinv[node];
    int eg = lane >> 4;
    int fl = lane & 15;
    float4 acc = make_float4(0.f, 0.f, 0.f, 0.f);

    for (int sb = p0; sb < pe; sb += 64) {
        int pl = sb + lane;
        int col = (pl < pe) ? edge_col[pl] : 0;
        int cnt = pe - sb;
        if (cnt > 64) cnt = 64;
        int kmax = (cnt + 3) >> 2;
        for (int k = 0; k < kmax; k++) {
            int s = k * 4 + eg;
            int c = __shfl(col, s);
            if (s < cnt) {
                float4 tv = ((const float4*)(t + (size_t)c * FD))[fl];
                acc.x += tv.x;
                acc.y += tv.y;
                acc.z += tv.z;
                acc.w += tv.w;
            }
        }
    }
    acc.x += __shfl_down(acc.x, 32); acc.y += __shfl_down(acc.y, 32);
    acc.z += __shfl_down(acc.z, 32); acc.w += __shfl_down(acc.w, 32);
    acc.x += __shfl_down(acc.x, 16); acc.y += __shfl_down(acc.y, 16);
    acc.z += __shfl_down(acc.z, 16); acc.w += __shfl_down(acc.w, 16);
    if (lane < 16) {
        float4* op = (float4*)(out + (size_t)node * FD);
        op[fl] = make_float4(dr * acc.x, dr * acc.y, dr * acc.z, dr * acc.w);
    }
}

extern "C" void kernel_launch(void* const* d_in, const int* in_sizes, int n_in,
                              void* d_out, int out_size, void* d_ws, size_t ws_size,
                              hipStream_t stream) {
    const float* x  = (const float*)d_in[0];
    const int*   ei = (const int*)d_in[1];
    const float* W1 = (const float*)d_in[2];
    const float* b1 = (const float*)d_in[3];
    const float* W2 = (const float*)d_in[4];
    const float* b2 = (const float*)d_in[5];
    const float* W3 = (const float*)d_in[6];
    const float* b3 = (const float*)d_in[7];
    float* out = (float*)d_out;

    char* ws = (char*)d_ws;
    size_t off = 0;
    float* A        = (float*)(ws + off); off += (size_t)BN * FD * 4;     // 20.48 MB
    float* Bb       = (float*)(ws + off); off += (size_t)BN * FD * 4;     // 20.48 MB
    int*   edge_col = (int*)(ws + off);   off += (size_t)TOTE * 4;        // 5.12 MB
    int*   row_start= (int*)(ws + off);   off += (size_t)(BN + 1) * 4;
    float* dinv     = (float*)(ws + off); off += (size_t)BN * 4;
    // rank (5.12 MB) + cnt (5.12 MB) alias B: B is first written by agg1,
    // stream-ordered after fill (the last reader of rank/cnt).
    int*   rank     = (int*)Bb;
    int*   cnt      = (int*)Bb + (size_t)TOTE;

    const int ab = NB * (NN / 4);           // 20000

    k_count_lds<<<NPA, 256, 0, stream>>>(ei, rank, cnt);
    k_scan_g<<<NB, 1024, 0, stream>>>(cnt, row_start, dinv);
    // CSR fill (blocks 0..4999) + A = dinv*(x@W1^T+b1) (blocks 5000+)
    k_fill_lin<<<FILLB + LINB, 256, 0, stream>>>(ei, row_start, rank, cnt,
                                                 edge_col, x, W1, b1, dinv, A);
    k_agg<<<ab, 256, 0, stream>>>(A, row_start, edge_col, dinv, Bb);   // B = h1
    k_linear<<<LINB, 256, 0, stream>>>(Bb, W2, b2, dinv, A);           // A = t2'
    k_agg<<<ab, 256, 0, stream>>>(A, row_start, edge_col, dinv, Bb);   // B = h2
    k_linear<<<LINB, 256, 0, stream>>>(Bb, W3, b3, dinv, A);           // A = t3'
    k_agg<<<ab, 256, 0, stream>>>(A, row_start, edge_col, dinv, out);  // out = h3
}